// Round 4
// baseline (24.898 us; speedup 1.0000x reference)
//
#include <hip/hip_runtime.h>
#include <hip/hip_bf16.h>

// PSRoIAlign: features [B, C=D*G*G, H, W] fp32, rois [N,5], out [N, D, G, G].
// G=7, SR=2, D=10.
//
// Round 4: amortize coordinate math across channels. One thread per
// (roi, bin, sample, d-half); each thread computes bilinear coords/weights
// ONCE and gathers 5 channel planes (20 loads, constant plane stride).
// 4-lane quads reduce the 2x2 sample grid via __shfl_xor.

#define G 7
#define SR 2
#define D_OUT 10
#define DG 2            // channel groups per (roi,bin,sample)
#define DPG (D_OUT/DG)  // 5 channels per thread

__global__ void psroi_align_kernel(const float* __restrict__ rois,
                                   const float* __restrict__ feat,
                                   const int* __restrict__ stride_p,
                                   int N, int B, int C, int H, int W,
                                   float* __restrict__ out) {
    int idx = blockIdx.x * blockDim.x + threadIdx.x;
    int total = N * (G * G) * DG * (SR * SR);
    if (idx >= total) return;

    int s   = idx & 3;          // sample: iy = s>>1, ix = s&1
    int t   = idx >> 2;
    int dg  = t & (DG - 1);
    int q   = t >> 1;
    int bin = q % (G * G);
    int r   = q / (G * G);
    int ph  = bin / G;
    int pw  = bin % G;
    int iy  = s >> 1;
    int ix  = s & 1;

    // stride may arrive as int32 or float32 bits; disambiguate.
    int iv = stride_p[0];
    float stride_f;
    if (iv > 0 && iv <= 65536) stride_f = (float)iv;
    else                       stride_f = __int_as_float(iv);
    float spatial_scale = 1.0f / stride_f;

    const float* roi = rois + (size_t)r * 5;
    int   b  = (int)roi[0];
    float sw = roi[1] * spatial_scale - 0.5f;
    float sh = roi[2] * spatial_scale - 0.5f;
    float ew = roi[3] * spatial_scale - 0.5f;
    float eh = roi[4] * spatial_scale - 0.5f;
    float roi_w = fmaxf(ew - sw, 0.1f);
    float roi_h = fmaxf(eh - sh, 0.1f);
    float bin_h = roi_h / (float)G;
    float bin_w = roi_w / (float)G;

    float y  = sh + ((float)ph + ((float)iy + 0.5f) / (float)SR) * bin_h;
    float x  = sw + ((float)pw + ((float)ix + 0.5f) / (float)SR) * bin_w;
    bool  vy = (y > -1.0f) && (y < (float)H);
    bool  vx = (x > -1.0f) && (x < (float)W);

    float cy = fmaxf(y, 0.0f);
    int  ylo = min((int)floorf(cy), H - 1);
    int  yhi = min(ylo + 1, H - 1);
    float ly = (ylo >= H - 1) ? 0.0f : (cy - (float)ylo);
    float hy = 1.0f - ly;

    float cx = fmaxf(x, 0.0f);
    int  xlo = min((int)floorf(cx), W - 1);
    int  xhi = min(xlo + 1, W - 1);
    float lx = (xlo >= W - 1) ? 0.0f : (cx - (float)xlo);
    float hx = 1.0f - lx;

    float w00 = hy * hx, w01 = hy * lx, w10 = ly * hx, w11 = ly * lx;

    const int HW = H * W;
    // first plane for this thread's channel group: c0 = (dg*DPG)*G*G + bin
    int c0 = dg * DPG * (G * G) + bin;
    const float* __restrict__ p = feat + ((size_t)b * C + c0) * (size_t)HW;
    const size_t pstride = (size_t)(G * G) * HW;

    float acc[DPG];
    if (vy && vx) {
        int o00 = ylo * W + xlo;
        int o01 = ylo * W + xhi;
        int o10 = yhi * W + xlo;
        int o11 = yhi * W + xhi;
#pragma unroll
        for (int j = 0; j < DPG; ++j) {
            acc[j] = w00 * p[o00] + w01 * p[o01] + w10 * p[o10] + w11 * p[o11];
            p += pstride;
        }
    } else {
#pragma unroll
        for (int j = 0; j < DPG; ++j) acc[j] = 0.0f;
    }

    // reduce 2x2 sample grid within each aligned 4-lane quad
#pragma unroll
    for (int j = 0; j < DPG; ++j) {
        float v = acc[j];
        v += __shfl_xor(v, 1);
        v += __shfl_xor(v, 2);
        if (s == 0) {
            int d = dg * DPG + j;
            out[(size_t)r * C + (size_t)d * (G * G) + bin] = v * (1.0f / (float)(SR * SR));
        }
    }
}

extern "C" void kernel_launch(void* const* d_in, const int* in_sizes, int n_in,
                              void* d_out, int out_size, void* d_ws, size_t ws_size,
                              hipStream_t stream) {
    const float* rois = (const float*)d_in[0];
    const float* feat = (const float*)d_in[1];
    const int*   strd = (const int*)d_in[2];
    float* out = (float*)d_out;

    int N = in_sizes[0] / 5;
    const int C = D_OUT * G * G;   // 490
    const int H = 160, W = 160;
    int B = in_sizes[1] / (C * H * W);

    int total = N * (G * G) * DG * (SR * SR);   // 200704
    int block = 64;                              // small blocks -> even CU spread
    int grid = (total + block - 1) / block;      // 3136
    psroi_align_kernel<<<grid, block, 0, stream>>>(rois, feat, strd, N, B, C, H, W, out);
}

// Round 5
// 22.866 us; speedup vs baseline: 1.0889x; 1.0889x over previous
//
#include <hip/hip_runtime.h>
#include <hip/hip_bf16.h>

// PSRoIAlign: features [B, C=D*G*G, H, W] fp32, rois [N,5], out [N, D, G, G].
// G=7, SR=2, D=10.
//
// Round 5: R2 layout (1 thread per (output, sample), 4-lane quad shfl reduce)
// + fused x-corner loads: one 8B (float2) load per y-row instead of two 4B
// loads. Halves divergent gather instruction count (62,720 -> 31,360).
// CDNA global loads support unaligned addresses; aligned(4) vector type lets
// the compiler emit global_load_dwordx2 at 4B-aligned (odd-float) offsets.

#define G 7
#define SR 2
#define D_OUT 10

typedef float f2_u __attribute__((ext_vector_type(2), aligned(4)));

__global__ void psroi_align_kernel(const float* __restrict__ rois,
                                   const float* __restrict__ feat,
                                   const int* __restrict__ stride_p,
                                   int N, int B, int C, int H, int W,
                                   float* __restrict__ out) {
    int idx = blockIdx.x * blockDim.x + threadIdx.x;
    int total = N * D_OUT * G * G * (SR * SR);
    if (idx >= total) return;

    int s       = idx & 3;        // sample id: iy = s>>1, ix = s&1
    int out_idx = idx >> 2;

    // stride may arrive as int32 or float32 bits; disambiguate.
    int iv = stride_p[0];
    float stride_f;
    if (iv > 0 && iv <= 65536) stride_f = (float)iv;
    else                       stride_f = __int_as_float(iv);
    float spatial_scale = 1.0f / stride_f;

    int pw = out_idx % G;
    int ph = (out_idx / G) % G;
    int d  = (out_idx / (G * G)) % D_OUT;
    int n  = out_idx / (G * G * D_OUT);

    const float* roi = rois + (size_t)n * 5;
    int   b  = (int)roi[0];
    float sw = roi[1] * spatial_scale - 0.5f;
    float sh = roi[2] * spatial_scale - 0.5f;
    float ew = roi[3] * spatial_scale - 0.5f;
    float eh = roi[4] * spatial_scale - 0.5f;
    float roi_w = fmaxf(ew - sw, 0.1f);
    float roi_h = fmaxf(eh - sh, 0.1f);
    float bin_h = roi_h / (float)G;
    float bin_w = roi_w / (float)G;

    // position-sensitive channel: c = (d*G + ph)*G + pw
    int c = (d * G + ph) * G + pw;
    const float* __restrict__ fplane = feat + ((size_t)b * C + c) * (size_t)(H * W);

    // this thread's single bilinear sample
    float offy = (s & 2) ? 0.75f : 0.25f;
    float offx = (s & 1) ? 0.75f : 0.25f;
    float y  = sh + ((float)ph + offy) * bin_h;
    float x  = sw + ((float)pw + offx) * bin_w;
    bool  vy = (y > -1.0f) && (y < (float)H);
    bool  vx = (x > -1.0f) && (x < (float)W);

    float cy = fmaxf(y, 0.0f);
    int  ylo = min((int)floorf(cy), H - 1);
    int  yhi = min(ylo + 1, H - 1);
    float ly = (ylo >= H - 1) ? 0.0f : (cy - (float)ylo);
    float hy = 1.0f - ly;

    float cx = fmaxf(x, 0.0f);
    int  xlo = min((int)floorf(cx), W - 1);
    float lx = (xlo >= W - 1) ? 0.0f : (cx - (float)xlo);
    float hx = 1.0f - lx;

    float val = 0.0f;
    if (vy && vx) {
        // fused x-corner load: pair (xbase, xbase+1); xbase = min(xlo, W-2)
        // guards the 4B-past-end case; when clamped, v00 = pair[1] and the
        // v01 weight (lx) is 0 with pair[1] a valid float (no 0*garbage).
        int xbase = min(xlo, W - 2);
        const f2_u* row0 = (const f2_u*)(fplane + (size_t)ylo * W + xbase);
        const f2_u* row1 = (const f2_u*)(fplane + (size_t)yhi * W + xbase);
        f2_u p0 = *row0;
        f2_u p1 = *row1;
        bool clamped = (xlo != xbase);
        float v00 = clamped ? p0.y : p0.x;
        float v01 = p0.y;
        float v10 = clamped ? p1.y : p1.x;
        float v11 = p1.y;
        val = hy * hx * v00 + hy * lx * v01 + ly * hx * v10 + ly * lx * v11;
    }

    // reduce the 2x2 sample grid across the 4-lane quad
    val += __shfl_xor(val, 1);
    val += __shfl_xor(val, 2);
    if (s == 0) out[out_idx] = val * (1.0f / (float)(SR * SR));
}

extern "C" void kernel_launch(void* const* d_in, const int* in_sizes, int n_in,
                              void* d_out, int out_size, void* d_ws, size_t ws_size,
                              hipStream_t stream) {
    const float* rois = (const float*)d_in[0];
    const float* feat = (const float*)d_in[1];
    const int*   strd = (const int*)d_in[2];
    float* out = (float*)d_out;

    int N = in_sizes[0] / 5;
    const int C = D_OUT * G * G;   // 490
    const int H = 160, W = 160;
    int B = in_sizes[1] / (C * H * W);

    int total = N * D_OUT * G * G * (SR * SR);
    int block = 256;
    int grid = (total + block - 1) / block;
    psroi_align_kernel<<<grid, block, 0, stream>>>(rois, feat, strd, N, B, C, H, W, out);
}